// Round 1
// baseline (2189.612 us; speedup 1.0000x reference)
//
#include <hip/hip_runtime.h>

// ---------------------------------------------------------------------------
// LSTMGRUHybrid: B=512, T=512, D=128, H=128 (4H=512), G=128 (3G=384), F=160, C=64
// Pipeline:
//   prep_x:    x fp32 -> bf16
//   prep_misc: weights -> bf16, bias_l = bih+bhh, transpose fc1/fco
//   gemm_nt:   gx_l = x_bf @ lstm_Wih^T + (bih+bhh)         [BT,512] bf16
//   lstm_scan: 32 blk x 16 batch rows, persistent Whh frags, fused LN -> lout bf16
//   gemm_nt:   gx_g = lout @ gru_Wih^T + gru_bih            [BT,384] bf16
//   gru_scan:  -> h_last [512,128] fp32
//   head:      LN->relu->fc1->LN->relu->fco -> out [512,64] fp32
// ---------------------------------------------------------------------------

typedef __attribute__((ext_vector_type(8))) short bf16x8;
typedef __attribute__((ext_vector_type(4))) float f32x4;
typedef __attribute__((ext_vector_type(4))) int i32x4;
typedef unsigned short u16;
typedef unsigned int u32;

#define BT 262144          // B*T
#define TT 512

__device__ __forceinline__ u16 f2bf(float f) {
  u32 u = __builtin_bit_cast(u32, f);
  u += 0x7fffu + ((u >> 16) & 1u);
  return (u16)(u >> 16);
}
__device__ __forceinline__ float bf2f(u16 h) {
  return __builtin_bit_cast(float, (u32)h << 16);
}
__device__ __forceinline__ u32 packbf2(float a, float b) {
  return (u32)f2bf(a) | ((u32)f2bf(b) << 16);
}
__device__ __forceinline__ bf16x8 ldg8(const u16* p) {
  return __builtin_bit_cast(bf16x8, *(const i32x4*)p);
}
__device__ __forceinline__ void g2lds16(const void* g, void* l) {
  __builtin_amdgcn_global_load_lds((const __attribute__((address_space(1))) void*)g,
                                   (__attribute__((address_space(3))) void*)l, 16, 0, 0);
}
__device__ __forceinline__ float sigm(float x) { return 1.f / (1.f + __expf(-x)); }
__device__ __forceinline__ float tanh_f(float x) { return 2.f / (1.f + __expf(-2.f * x)) - 1.f; }

// ---------------------------------------------------------------------------
// prep kernels
// ---------------------------------------------------------------------------
__global__ void prep_x(const float* __restrict__ x, u16* __restrict__ xb) {
  size_t i = ((size_t)blockIdx.x * 256 + threadIdx.x) * 4;
  float4 v = *(const float4*)(x + i);
  *(uint2*)(xb + i) = make_uint2(packbf2(v.x, v.y), packbf2(v.z, v.w));
}

__global__ void prep_misc(
    const float* __restrict__ wihl, const float* __restrict__ whhl,
    const float* __restrict__ wihg, const float* __restrict__ whhg,
    const float* __restrict__ bihl, const float* __restrict__ bhhl,
    const float* __restrict__ fc1W, const float* __restrict__ fcoW,
    u16* __restrict__ wihlb, u16* __restrict__ whhlb,
    u16* __restrict__ wihgb, u16* __restrict__ whhgb,
    float* __restrict__ biasl, float* __restrict__ fc1Wt, float* __restrict__ fcoWt) {
  int i = blockIdx.x * 256 + threadIdx.x;
  if (i < 65536) {
    wihlb[i] = f2bf(wihl[i]);
  } else if (i < 131072) {
    int k = i - 65536; whhlb[k] = f2bf(whhl[k]);
  } else if (i < 180224) {
    int k = i - 131072; wihgb[k] = f2bf(wihg[k]);
  } else if (i < 229376) {
    int k = i - 180224; whhgb[k] = f2bf(whhg[k]);
  } else if (i < 229888) {
    int k = i - 229376; biasl[k] = bihl[k] + bhhl[k];
  } else if (i < 250368) {
    int k = i - 229888;                       // fc1Wt[g*160+f] = fc1W[f*128+g]
    fc1Wt[k] = fc1W[(k % 160) * 128 + (k / 160)];
  } else if (i < 260608) {
    int k = i - 250368;                       // fcoWt[f*64+c] = fcoW[c*160+f]
    fcoWt[k] = fcoW[(k % 64) * 160 + (k / 64)];
  }
}

// ---------------------------------------------------------------------------
// NT GEMM: C[M,N] bf16 = A[M,128] bf16 @ Bw[N,128]^T + bias[N]; tile 128x128
// ---------------------------------------------------------------------------
__global__ __launch_bounds__(256) void gemm_nt(
    const u16* __restrict__ A, const u16* __restrict__ Bw,
    const float* __restrict__ bias, u16* __restrict__ C, int N) {
  __shared__ __align__(16) u16 sA[128 * 128];
  __shared__ __align__(16) u16 sB[128 * 128];
  const int tid = threadIdx.x;
  const int w = tid >> 6, l = tid & 63;
  const size_t m0 = (size_t)blockIdx.x * 128;
  const int n0 = blockIdx.y * 128;
  const char* gA = (const char*)(A + m0 * 128);
  const char* gB = (const char*)(Bw + (size_t)n0 * 128);
  char* lA = (char*)sA;
  char* lB = (char*)sB;
#pragma unroll
  for (int i = 0; i < 8; i++) {
    int ubase = (w * 8 + i) << 10;   // 1KB per wave-inst
    int off = ubase + (l << 4);
    g2lds16(gA + off, lA + ubase);
    g2lds16(gB + off, lB + ubase);
  }
  __syncthreads();
  const int mq = (w >> 1) * 64, nq = (w & 1) * 64;
  f32x4 acc[4][4];
#pragma unroll
  for (int i = 0; i < 4; i++)
#pragma unroll
    for (int j = 0; j < 4; j++) acc[i][j] = (f32x4){0.f, 0.f, 0.f, 0.f};
#pragma unroll
  for (int k0 = 0; k0 < 4; k0++) {
    const int koff = k0 * 32 + (l >> 4) * 8;
    bf16x8 af[4], bf[4];
#pragma unroll
    for (int i = 0; i < 4; i++) af[i] = ldg8(&sA[(mq + i * 16 + (l & 15)) * 128 + koff]);
#pragma unroll
    for (int j = 0; j < 4; j++) bf[j] = ldg8(&sB[(nq + j * 16 + (l & 15)) * 128 + koff]);
#pragma unroll
    for (int i = 0; i < 4; i++)
#pragma unroll
      for (int j = 0; j < 4; j++)
        acc[i][j] = __builtin_amdgcn_mfma_f32_16x16x32_bf16(af[i], bf[j], acc[i][j], 0, 0, 0);
  }
  float bv[4];
#pragma unroll
  for (int j = 0; j < 4; j++) bv[j] = bias[n0 + nq + j * 16 + (l & 15)];
  __syncthreads();
  u16* sOut = sA;  // reuse
#pragma unroll
  for (int i = 0; i < 4; i++)
#pragma unroll
    for (int j = 0; j < 4; j++)
#pragma unroll
      for (int r = 0; r < 4; r++)
        sOut[(mq + i * 16 + (l >> 4) * 4 + r) * 128 + nq + j * 16 + (l & 15)] =
            f2bf(acc[i][j][r] + bv[j]);
  __syncthreads();
#pragma unroll
  for (int p = 0; p < 8; p++) {
    int e = (p * 256 + tid) * 8;  // element index within 128x128 tile
    int row = e >> 7, col = e & 127;
    *(i32x4*)(C + (m0 + row) * (size_t)N + n0 + col) = *(const i32x4*)&sOut[e];
  }
}

// ---------------------------------------------------------------------------
// LSTM scan + fused LayerNorm. 32 blocks x 512 threads; 16 batch rows / block.
// ---------------------------------------------------------------------------
__global__ __launch_bounds__(512) void lstm_scan(
    const u16* __restrict__ gx,   // [BT][512] bf16 (x-proj + bih + bhh)
    const u16* __restrict__ whh,  // [512][128] bf16
    const float* __restrict__ lng, const float* __restrict__ lnb,
    u16* __restrict__ lout) {     // [B][T][128] bf16, LayerNormed
  const int tid = threadIdx.x;
  const int w = tid >> 6, l = tid & 63;
  const int b0 = blockIdx.x * 16;
  __shared__ __align__(16) u16 hbuf[16 * 136];   // padded rows: 2-way banks only
  __shared__ __align__(16) float mm[16 * 516];   // padded stride

  // persistent Whh B-fragments: wave w owns output cols [w*64, w*64+64)
  bf16x8 wf[4][4];
#pragma unroll
  for (int nt = 0; nt < 4; nt++)
#pragma unroll
    for (int k0 = 0; k0 < 4; k0++) {
      int n = w * 64 + nt * 16 + (l & 15);
      int k = k0 * 32 + (l >> 4) * 8;
      wf[nt][k0] = ldg8(&whh[n * 128 + k]);
    }
  const int gm = tid >> 5, j4 = tid & 31;  // gate thread: row gm, cols j4*4..+4
  float c[4] = {0.f, 0.f, 0.f, 0.f};
  const float4 lg = *(const float4*)&lng[j4 * 4];
  const float4 lb = *(const float4*)&lnb[j4 * 4];
  for (int i = tid; i < 16 * 136; i += 512) hbuf[i] = 0;
  const size_t growbase = (size_t)(b0 + gm) * TT * 512 + (size_t)j4 * 4;
  u32 gq[4][2], gn[4][2];
  {
    const u16* p = gx + growbase;
#pragma unroll
    for (int g = 0; g < 4; g++) {
      uint2 v = *(const uint2*)(p + g * 128);
      gq[g][0] = v.x; gq[g][1] = v.y;
    }
  }
  __syncthreads();
#pragma unroll 1
  for (int t = 0; t < TT; t++) {
    // --- matmul: h_prev @ Whh^T ---
    bf16x8 af[4];
#pragma unroll
    for (int k0 = 0; k0 < 4; k0++)
      af[k0] = ldg8(&hbuf[(l & 15) * 136 + k0 * 32 + (l >> 4) * 8]);
    f32x4 acc[4];
#pragma unroll
    for (int nt = 0; nt < 4; nt++) acc[nt] = (f32x4){0.f, 0.f, 0.f, 0.f};
#pragma unroll
    for (int k0 = 0; k0 < 4; k0++)
#pragma unroll
      for (int nt = 0; nt < 4; nt++)
        acc[nt] = __builtin_amdgcn_mfma_f32_16x16x32_bf16(af[k0], wf[nt][k0], acc[nt], 0, 0, 0);
    // --- prefetch next step's gx ---
    {
      int tn = (t + 1 < TT) ? (t + 1) : t;
      const u16* p = gx + growbase + (size_t)tn * 512;
#pragma unroll
      for (int g = 0; g < 4; g++) {
        uint2 v = *(const uint2*)(p + g * 128);
        gn[g][0] = v.x; gn[g][1] = v.y;
      }
    }
#pragma unroll
    for (int nt = 0; nt < 4; nt++)
#pragma unroll
      for (int r = 0; r < 4; r++)
        mm[((l >> 4) * 4 + r) * 516 + w * 64 + nt * 16 + (l & 15)] = acc[nt][r];
    __syncthreads();
    // --- gate phase ---
    const float* pm = &mm[gm * 516 + j4 * 4];
    float4 m_i = *(const float4*)(pm);
    float4 m_f = *(const float4*)(pm + 128);
    float4 m_g = *(const float4*)(pm + 256);
    float4 m_o = *(const float4*)(pm + 384);
    const float* mi = (const float*)&m_i;
    const float* mf = (const float*)&m_f;
    const float* mg = (const float*)&m_g;
    const float* mo = (const float*)&m_o;
    float hv[4], s1 = 0.f, s2 = 0.f;
#pragma unroll
    for (int e = 0; e < 4; e++) {
      float pi = mi[e] + bf2f((u16)(gq[0][e >> 1] >> ((e & 1) * 16)));
      float pf = mf[e] + bf2f((u16)(gq[1][e >> 1] >> ((e & 1) * 16)));
      float pg = mg[e] + bf2f((u16)(gq[2][e >> 1] >> ((e & 1) * 16)));
      float po = mo[e] + bf2f((u16)(gq[3][e >> 1] >> ((e & 1) * 16)));
      c[e] = sigm(pf) * c[e] + sigm(pi) * tanh_f(pg);
      float h = sigm(po) * tanh_f(c[e]);
      hv[e] = h; s1 += h; s2 += h * h;
    }
    *(uint2*)((char*)hbuf + gm * 272 + j4 * 8) =
        make_uint2(packbf2(hv[0], hv[1]), packbf2(hv[2], hv[3]));
    // fused LayerNorm over the 128 h of row gm (32-lane group reduction)
#pragma unroll
    for (int msk = 1; msk < 32; msk <<= 1) {
      s1 += __shfl_xor(s1, msk);
      s2 += __shfl_xor(s2, msk);
    }
    float mean = s1 * 0.0078125f;
    float var = s2 * 0.0078125f - mean * mean;
    float rs = rsqrtf(var + 1e-5f);
    float y0 = (hv[0] - mean) * rs * lg.x + lb.x;
    float y1 = (hv[1] - mean) * rs * lg.y + lb.y;
    float y2 = (hv[2] - mean) * rs * lg.z + lb.z;
    float y3 = (hv[3] - mean) * rs * lg.w + lb.w;
    *(uint2*)(lout + ((size_t)(b0 + gm) * TT + t) * 128 + j4 * 4) =
        make_uint2(packbf2(y0, y1), packbf2(y2, y3));
#pragma unroll
    for (int g = 0; g < 4; g++) { gq[g][0] = gn[g][0]; gq[g][1] = gn[g][1]; }
    __syncthreads();
  }
}

// ---------------------------------------------------------------------------
// GRU scan -> final hidden only. Same skeleton, 3 gates (r,z,n).
// ---------------------------------------------------------------------------
__global__ __launch_bounds__(512) void gru_scan(
    const u16* __restrict__ gx,   // [BT][384] bf16 (x-proj + bih)
    const u16* __restrict__ whh,  // [384][128] bf16
    const float* __restrict__ bhh,
    float* __restrict__ hlast) {  // [512][128] fp32
  const int tid = threadIdx.x;
  const int w = tid >> 6, l = tid & 63;
  const int b0 = blockIdx.x * 16;
  __shared__ __align__(16) u16 hbuf[16 * 136];
  __shared__ __align__(16) float mm[16 * 388];

  bf16x8 wf[3][4];  // wave w owns cols [w*48, w*48+48)
#pragma unroll
  for (int nt = 0; nt < 3; nt++)
#pragma unroll
    for (int k0 = 0; k0 < 4; k0++) {
      int n = w * 48 + nt * 16 + (l & 15);
      int k = k0 * 32 + (l >> 4) * 8;
      wf[nt][k0] = ldg8(&whh[n * 128 + k]);
    }
  const int gm = tid >> 5, j4 = tid & 31;
  float hp[4] = {0.f, 0.f, 0.f, 0.f};
  const float4 bhr = *(const float4*)&bhh[0 + j4 * 4];
  const float4 bhz = *(const float4*)&bhh[128 + j4 * 4];
  const float4 bhn = *(const float4*)&bhh[256 + j4 * 4];
  const float* br = (const float*)&bhr;
  const float* bz = (const float*)&bhz;
  const float* bn = (const float*)&bhn;
  for (int i = tid; i < 16 * 136; i += 512) hbuf[i] = 0;
  const size_t growbase = (size_t)(b0 + gm) * TT * 384 + (size_t)j4 * 4;
  u32 gq[3][2], gn[3][2];
  {
    const u16* p = gx + growbase;
#pragma unroll
    for (int g = 0; g < 3; g++) {
      uint2 v = *(const uint2*)(p + g * 128);
      gq[g][0] = v.x; gq[g][1] = v.y;
    }
  }
  __syncthreads();
#pragma unroll 1
  for (int t = 0; t < TT; t++) {
    bf16x8 af[4];
#pragma unroll
    for (int k0 = 0; k0 < 4; k0++)
      af[k0] = ldg8(&hbuf[(l & 15) * 136 + k0 * 32 + (l >> 4) * 8]);
    f32x4 acc[3];
#pragma unroll
    for (int nt = 0; nt < 3; nt++) acc[nt] = (f32x4){0.f, 0.f, 0.f, 0.f};
#pragma unroll
    for (int k0 = 0; k0 < 4; k0++)
#pragma unroll
      for (int nt = 0; nt < 3; nt++)
        acc[nt] = __builtin_amdgcn_mfma_f32_16x16x32_bf16(af[k0], wf[nt][k0], acc[nt], 0, 0, 0);
    {
      int tn = (t + 1 < TT) ? (t + 1) : t;
      const u16* p = gx + growbase + (size_t)tn * 384;
#pragma unroll
      for (int g = 0; g < 3; g++) {
        uint2 v = *(const uint2*)(p + g * 128);
        gn[g][0] = v.x; gn[g][1] = v.y;
      }
    }
#pragma unroll
    for (int nt = 0; nt < 3; nt++)
#pragma unroll
      for (int r = 0; r < 4; r++)
        mm[((l >> 4) * 4 + r) * 388 + w * 48 + nt * 16 + (l & 15)] = acc[nt][r];
    __syncthreads();
    const float* pm = &mm[gm * 388 + j4 * 4];
    float4 m_r = *(const float4*)(pm);
    float4 m_z = *(const float4*)(pm + 128);
    float4 m_n = *(const float4*)(pm + 256);
    const float* mr = (const float*)&m_r;
    const float* mz = (const float*)&m_z;
    const float* mn = (const float*)&m_n;
#pragma unroll
    for (int e = 0; e < 4; e++) {
      float gxr = bf2f((u16)(gq[0][e >> 1] >> ((e & 1) * 16)));
      float gxz = bf2f((u16)(gq[1][e >> 1] >> ((e & 1) * 16)));
      float gxn = bf2f((u16)(gq[2][e >> 1] >> ((e & 1) * 16)));
      float r = sigm(gxr + mr[e] + br[e]);
      float z = sigm(gxz + mz[e] + bz[e]);
      float n = tanh_f(gxn + r * (mn[e] + bn[e]));
      hp[e] = (1.f - z) * n + z * hp[e];
    }
    *(uint2*)((char*)hbuf + gm * 272 + j4 * 8) =
        make_uint2(packbf2(hp[0], hp[1]), packbf2(hp[2], hp[3]));
#pragma unroll
    for (int g = 0; g < 3; g++) { gq[g][0] = gn[g][0]; gq[g][1] = gn[g][1]; }
    __syncthreads();
  }
  *(float4*)(hlast + (size_t)(b0 + gm) * 128 + j4 * 4) =
      make_float4(hp[0], hp[1], hp[2], hp[3]);
}

// ---------------------------------------------------------------------------
// Head: LN(gru) -> relu -> fc1 -> LN(fc1) -> relu -> fco. One block per row.
// ---------------------------------------------------------------------------
__global__ __launch_bounds__(256) void head(
    const float* __restrict__ hlast,
    const float* __restrict__ g1, const float* __restrict__ b1,
    const float* __restrict__ fc1Wt, const float* __restrict__ fc1b,
    const float* __restrict__ g2, const float* __restrict__ b2,
    const float* __restrict__ fcoWt, const float* __restrict__ fcob,
    float* __restrict__ out) {
  const int b = blockIdx.x, tid = threadIdx.x;
  __shared__ float yv[128];
  __shared__ float zv[160];
  __shared__ float red[8];
  float v = (tid < 128) ? hlast[b * 128 + tid] : 0.f;
  float p1 = v, p2 = v * v;
#pragma unroll
  for (int m = 1; m < 64; m <<= 1) { p1 += __shfl_xor(p1, m); p2 += __shfl_xor(p2, m); }
  if ((tid & 63) == 0) { red[(tid >> 6) * 2] = p1; red[(tid >> 6) * 2 + 1] = p2; }
  __syncthreads();
  float s1 = red[0] + red[2] + red[4] + red[6];
  float s2 = red[1] + red[3] + red[5] + red[7];
  float mean = s1 * (1.f / 128.f);
  float var = s2 * (1.f / 128.f) - mean * mean;
  float rs = rsqrtf(var + 1e-5f);
  if (tid < 128) yv[tid] = fmaxf((v - mean) * rs * g1[tid] + b1[tid], 0.f);
  __syncthreads();
  float z = 0.f;
  if (tid < 160) {
    z = fc1b[tid];
    for (int g = 0; g < 128; g++) z += yv[g] * fc1Wt[g * 160 + tid];
  }
  float q1 = (tid < 160) ? z : 0.f;
  float q2 = (tid < 160) ? z * z : 0.f;
#pragma unroll
  for (int m = 1; m < 64; m <<= 1) { q1 += __shfl_xor(q1, m); q2 += __shfl_xor(q2, m); }
  __syncthreads();
  if ((tid & 63) == 0) { red[(tid >> 6) * 2] = q1; red[(tid >> 6) * 2 + 1] = q2; }
  __syncthreads();
  s1 = red[0] + red[2] + red[4] + red[6];
  s2 = red[1] + red[3] + red[5] + red[7];
  mean = s1 * (1.f / 160.f);
  var = s2 * (1.f / 160.f) - mean * mean;
  rs = rsqrtf(var + 1e-5f);
  if (tid < 160) zv[tid] = fmaxf((z - mean) * rs * g2[tid] + b2[tid], 0.f);
  __syncthreads();
  if (tid < 64) {
    float o = fcob[tid];
    for (int f = 0; f < 160; f++) o += zv[f] * fcoWt[f * 64 + tid];
    out[b * 64 + tid] = o;
  }
}

// ---------------------------------------------------------------------------
// workspace layout (bytes) — total ~404 MB; gx region shared by LSTM/GRU phases
// ---------------------------------------------------------------------------
static constexpr size_t OFF_XBF   = 0;                          // 67,108,864
static constexpr size_t OFF_GX    = 67108864;                   // 268,435,456
static constexpr size_t OFF_LOUT  = OFF_GX + 268435456;         // 67,108,864
static constexpr size_t OFF_WIHL  = OFF_LOUT + 67108864;        // 131,072
static constexpr size_t OFF_WHHL  = OFF_WIHL + 131072;          // 131,072
static constexpr size_t OFF_WIHG  = OFF_WHHL + 131072;          // 98,304
static constexpr size_t OFF_WHHG  = OFF_WIHG + 98304;           // 98,304
static constexpr size_t OFF_BIASL = OFF_WHHG + 98304;           // 2,048
static constexpr size_t OFF_FC1T  = OFF_BIASL + 2048;           // 81,920
static constexpr size_t OFF_FCOT  = OFF_FC1T + 81920;           // 40,960
static constexpr size_t OFF_HLAST = OFF_FCOT + 40960;           // 262,144

extern "C" void kernel_launch(void* const* d_in, const int* in_sizes, int n_in,
                              void* d_out, int out_size, void* d_ws, size_t ws_size,
                              hipStream_t stream) {
  (void)in_sizes; (void)n_in; (void)out_size; (void)ws_size;
  const float* x    = (const float*)d_in[0];
  const float* lWih = (const float*)d_in[1];
  const float* lWhh = (const float*)d_in[2];
  const float* lbih = (const float*)d_in[3];
  const float* lbhh = (const float*)d_in[4];
  const float* gWih = (const float*)d_in[5];
  const float* gWhh = (const float*)d_in[6];
  const float* gbih = (const float*)d_in[7];
  const float* gbhh = (const float*)d_in[8];
  const float* lnLg = (const float*)d_in[9];
  const float* lnLb = (const float*)d_in[10];
  const float* lnGg = (const float*)d_in[11];
  const float* lnGb = (const float*)d_in[12];
  const float* fc1W = (const float*)d_in[13];
  const float* fc1b = (const float*)d_in[14];
  const float* lnFg = (const float*)d_in[15];
  const float* lnFb = (const float*)d_in[16];
  const float* fcoW = (const float*)d_in[17];
  const float* fcob = (const float*)d_in[18];

  char* ws = (char*)d_ws;
  u16* xbf    = (u16*)(ws + OFF_XBF);
  u16* gx     = (u16*)(ws + OFF_GX);
  u16* lout   = (u16*)(ws + OFF_LOUT);
  u16* wihlb  = (u16*)(ws + OFF_WIHL);
  u16* whhlb  = (u16*)(ws + OFF_WHHL);
  u16* wihgb  = (u16*)(ws + OFF_WIHG);
  u16* whhgb  = (u16*)(ws + OFF_WHHG);
  float* biasl = (float*)(ws + OFF_BIASL);
  float* fc1Wt = (float*)(ws + OFF_FC1T);
  float* fcoWt = (float*)(ws + OFF_FCOT);
  float* hlast = (float*)(ws + OFF_HLAST);
  float* out   = (float*)d_out;

  prep_x<<<32768, 256, 0, stream>>>(x, xbf);
  prep_misc<<<1024, 256, 0, stream>>>(lWih, lWhh, gWih, gWhh, lbih, lbhh, fc1W, fcoW,
                                      wihlb, whhlb, wihgb, whhgb, biasl, fc1Wt, fcoWt);
  gemm_nt<<<dim3(2048, 4), 256, 0, stream>>>(xbf, wihlb, biasl, gx, 512);
  lstm_scan<<<32, 512, 0, stream>>>(gx, whhlb, lnLg, lnLb, lout);
  gemm_nt<<<dim3(2048, 3), 256, 0, stream>>>(lout, wihgb, gbih, gx, 384);
  gru_scan<<<32, 512, 0, stream>>>(gx, whhgb, gbhh, hlast);
  head<<<512, 256, 0, stream>>>(hlast, lnGg, lnGb, fc1Wt, fc1b, lnFg, lnFb, fcoWt, fcob, out);
}